// Round 8
// baseline (63.564 us; speedup 1.0000x reference)
//
#include <hip/hip_runtime.h>

// FOFE encoding:
//   out[w, c] = sum over positions k with x[w,k]==c && c!=0 of f^(#nonzero strictly after k)
// x: [num_words, 32] int32, f: scalar f32, out: [num_words, 256] f32.
//
// A/B experiment vs round 7: IDENTICAL structure (one-shot waves, 4096
// blocks x 4 waves, 16 words per wave as four quads, prologue loads, four
// back-to-back DS chains), but PLAIN global stores instead of nontemporal.
// Isolates the nt-store variable that round 5 bundled with the 2-quad
// unroll: if nt was capping write-burst efficiency, this wins; if nt was
// the real round-5 lever, this regresses to ~70 us.

constexpr int WORD_LEN = 32;
constexpr int VOCAB    = 256;
constexpr int WAVES_PER_BLOCK = 4;    // 256 threads
constexpr int WORDS_PER_WAVE  = 16;   // 4 quads

typedef float f32x4 __attribute__((ext_vector_type(4)));
typedef int   i32x2 __attribute__((ext_vector_type(2)));

__global__ __launch_bounds__(256) void fofe_kernel(
    const int* __restrict__ x,
    const float* __restrict__ fptr,
    float* __restrict__ out,
    int num_words)
{
    // [wave][word-in-quad][vocab] : 16 KiB per block; all 4 stages reuse
    // the same 4 tiles sequentially (DS program order keeps it safe)
    __shared__ float tiles[WAVES_PER_BLOCK][4][VOCAB];

    const int lane = threadIdx.x & 63;
    const int wv   = threadIdx.x >> 6;
    const int grp  = lane >> 4;          // which word of the quad (0..3)
    const int j    = lane & 15;          // char-pair index: positions 2j, 2j+1

    const int gw = blockIdx.x * WAVES_PER_BLOCK + wv;      // global wave id
    const int w0 = gw * WORDS_PER_WAVE;                    // first word

    const i32x2* x2 = reinterpret_cast<const i32x2*>(x);   // 16 i32x2 per word

    // ---- prologue: issue all 4 quads' char loads ----
    i32x2 c[4];
#pragma unroll
    for (int q = 0; q < 4; ++q) {
        c[q] = (i32x2)(0);
        if (w0 + 4 * q + grp < num_words)
            c[q] = x2[(size_t)(w0 + 4 * q) * 16 + lane];
    }

    const float f  = *fptr;
    const float lf = __log2f(f);

    float (*mytiles)[VOCAB] = tiles[wv];
    float*  tile = mytiles[grp];                            // this lane's word tile
    f32x4*  t4   = reinterpret_cast<f32x4*>(mytiles);       // 256 f32x4 (all 4 tiles)

    // ---- four independent stages, queued back-to-back on the DS pipe ----
#pragma unroll
    for (int q = 0; q < 4; ++q) {
        const int wq = w0 + 4 * q;
        const i32x2 cc = c[q];

        const bool nzE = (cc.x != 0);
        const bool nzO = (cc.y != 0);
        const unsigned long long mE = __ballot(nzE);
        const unsigned long long mO = __ballot(nzO);
        const unsigned int mEg = (unsigned int)(mE >> (grp * 16)) & 0xFFFFu;
        const unsigned int mOg = (unsigned int)(mO >> (grp * 16)) & 0xFFFFu;
        // nonzeros strictly after position 2j / 2j+1 within this word:
        const int sE = __popc(mEg >> (j + 1)) + __popc(mOg >> j);
        const int sO = __popc(mEg >> (j + 1)) + __popc(mOg >> (j + 1));

        float wE = 0.0f, wO = 0.0f;
        if (nzE) wE = (sE == 0) ? 1.0f : exp2f((float)sE * lf);
        if (nzO) wO = (sO == 0) ? 1.0f : exp2f((float)sO * lf);

        // zero all 4 tiles: 4 KiB = 4 x ds_write_b128 per lane
        const f32x4 z = (f32x4)(0.0f);
        t4[lane]       = z;
        t4[lane + 64]  = z;
        t4[lane + 128] = z;
        t4[lane + 192] = z;

        // scatter (wave-private tiles; DS pipe in-order => no barrier)
        if (nzE) atomicAdd(&tile[cc.x], wE);
        if (nzO) atomicAdd(&tile[cc.y], wO);

        // read back & store 4 KiB contiguous, fully coalesced (PLAIN stores)
        const f32x4 v0 = t4[lane];
        const f32x4 v1 = t4[lane + 64];
        const f32x4 v2 = t4[lane + 128];
        const f32x4 v3 = t4[lane + 192];
        f32x4* o4 = reinterpret_cast<f32x4*>(out + (size_t)wq * VOCAB);
        if (wq + 0 < num_words) o4[lane]       = v0;
        if (wq + 1 < num_words) o4[lane + 64]  = v1;
        if (wq + 2 < num_words) o4[lane + 128] = v2;
        if (wq + 3 < num_words) o4[lane + 192] = v3;
    }
}

extern "C" void kernel_launch(void* const* d_in, const int* in_sizes, int n_in,
                              void* d_out, int out_size, void* d_ws, size_t ws_size,
                              hipStream_t stream)
{
    const int*   x    = (const int*)d_in[0];
    const float* fptr = (const float*)d_in[1];
    float*       out  = (float*)d_out;

    const int num_words = in_sizes[0] / WORD_LEN;
    const int waves  = (num_words + WORDS_PER_WAVE - 1) / WORDS_PER_WAVE;
    const int blocks = (waves + WAVES_PER_BLOCK - 1) / WAVES_PER_BLOCK;

    fofe_kernel<<<blocks, 256, 0, stream>>>(x, fptr, out, num_words);
}

// Round 9
// 59.234 us; speedup vs baseline: 1.0731x; 1.0731x over previous
//
#include <hip/hip_runtime.h>

// FOFE encoding:
//   out[w, c] = sum over positions k with x[w,k]==c && c!=0 of f^(#nonzero strictly after k)
// x: [num_words, 32] int32, f: scalar f32, out: [num_words, 256] f32.
//
// Persistent-wave experiment: 512 blocks x 4 waves = 2048 long-lived waves,
// each looping 32 quad-iterations (128 words/wave) with 2-deep prefetch.
// Mimics the rocclr fill's profile (6.8-7.0 TB/s at ~3 waves/CU): few,
// long-lived write streams with steady cadence instead of 16K short waves.
// Per quad (4 words): one int2 load per lane; 4 wave-private 256-float LDS
// tiles (zero -> atomic scatter -> b128 readback, DS pipe in-order, no
// barriers); 4 KiB contiguous nontemporal stores. Active write front =
// 2048 waves x 4 KiB = 8 MiB band sweeping the output linearly.

constexpr int WORD_LEN = 32;
constexpr int VOCAB    = 256;
constexpr int WAVES_PER_BLOCK = 4;   // 256 threads
constexpr int NUM_BLOCKS      = 512; // 2 blocks/CU -> 8 waves/CU

typedef float f32x4 __attribute__((ext_vector_type(4)));
typedef int   i32x2 __attribute__((ext_vector_type(2)));

__global__ __launch_bounds__(256) void fofe_kernel(
    const int* __restrict__ x,
    const float* __restrict__ fptr,
    float* __restrict__ out,
    int num_words)
{
    // [wave][word-in-quad][vocab] : 16 KiB per block, reused every iteration
    __shared__ float tiles[WAVES_PER_BLOCK][4][VOCAB];

    const int lane = threadIdx.x & 63;
    const int wv   = threadIdx.x >> 6;
    const int grp  = lane >> 4;          // which word of the quad (0..3)
    const int j    = lane & 15;          // char-pair index: positions 2j, 2j+1

    const int gw = blockIdx.x * WAVES_PER_BLOCK + wv;      // 0..2047
    const int nw = NUM_BLOCKS * WAVES_PER_BLOCK;           // 2048 waves
    const int nquads = (num_words + 3) >> 2;

    const i32x2* x2 = reinterpret_cast<const i32x2*>(x);   // 16 i32x2 per word

    const float f  = *fptr;
    const float lf = __log2f(f);

    float (*mytiles)[VOCAB] = tiles[wv];
    float*  tile = mytiles[grp];                            // this lane's word tile
    f32x4*  t4   = reinterpret_cast<f32x4*>(mytiles);       // 256 f32x4 (all 4 tiles)

    auto load_quad = [&](int q) -> i32x2 {
        i32x2 c = (i32x2)(0);
        if (q < nquads && q * 4 + grp < num_words)
            c = x2[(size_t)q * 64 + lane];                  // 4 words * 16 i32x2
        return c;
    };

    auto process = [&](int wq, i32x2 cc) {
        const bool nzE = (cc.x != 0);
        const bool nzO = (cc.y != 0);
        const unsigned long long mE = __ballot(nzE);
        const unsigned long long mO = __ballot(nzO);
        const unsigned int mEg = (unsigned int)(mE >> (grp * 16)) & 0xFFFFu;
        const unsigned int mOg = (unsigned int)(mO >> (grp * 16)) & 0xFFFFu;
        // nonzeros strictly after position 2j / 2j+1 within this word:
        const int sE = __popc(mEg >> (j + 1)) + __popc(mOg >> j);
        const int sO = __popc(mEg >> (j + 1)) + __popc(mOg >> (j + 1));

        float wE = 0.0f, wO = 0.0f;
        if (nzE) wE = (sE == 0) ? 1.0f : exp2f((float)sE * lf);
        if (nzO) wO = (sO == 0) ? 1.0f : exp2f((float)sO * lf);

        // zero all 4 tiles: 4 KiB = 4 x ds_write_b128 per lane
        const f32x4 z = (f32x4)(0.0f);
        t4[lane]       = z;
        t4[lane + 64]  = z;
        t4[lane + 128] = z;
        t4[lane + 192] = z;

        // scatter (wave-private tiles; DS pipe in-order => no barrier)
        if (nzE) atomicAdd(&tile[cc.x], wE);
        if (nzO) atomicAdd(&tile[cc.y], wO);

        // read back & stream out 4 KiB contiguous, fully coalesced, nt
        const f32x4 v0 = t4[lane];
        const f32x4 v1 = t4[lane + 64];
        const f32x4 v2 = t4[lane + 128];
        const f32x4 v3 = t4[lane + 192];
        f32x4* o4 = reinterpret_cast<f32x4*>(out + (size_t)wq * VOCAB);
        if (wq + 0 < num_words) __builtin_nontemporal_store(v0, &o4[lane]);
        if (wq + 1 < num_words) __builtin_nontemporal_store(v1, &o4[lane + 64]);
        if (wq + 2 < num_words) __builtin_nontemporal_store(v2, &o4[lane + 128]);
        if (wq + 3 < num_words) __builtin_nontemporal_store(v3, &o4[lane + 192]);
    };

    // ---- 2-deep prefetch pipeline over 32 quad-iterations ----
    i32x2 c0 = load_quad(gw);
    i32x2 c1 = load_quad(gw + nw);

    for (int q = gw; q < nquads; q += nw) {
        i32x2 cp = load_quad(q + 2 * nw);   // issue 2-ahead load
        process(q * 4, c0);                 // consume current
        c0 = c1;
        c1 = cp;
    }
}

extern "C" void kernel_launch(void* const* d_in, const int* in_sizes, int n_in,
                              void* d_out, int out_size, void* d_ws, size_t ws_size,
                              hipStream_t stream)
{
    const int*   x    = (const int*)d_in[0];
    const float* fptr = (const float*)d_in[1];
    float*       out  = (float*)d_out;

    const int num_words = in_sizes[0] / WORD_LEN;

    fofe_kernel<<<NUM_BLOCKS, 256, 0, stream>>>(x, fptr, out, num_words);
}

// Round 10
// 57.902 us; speedup vs baseline: 1.0978x; 1.0230x over previous
//
#include <hip/hip_runtime.h>

// FOFE encoding:
//   out[w, c] = sum over positions k with x[w,k]==c && c!=0 of f^(#nonzero strictly after k)
// x: [num_words, 32] int32, f: scalar f32, out: [num_words, 256] f32.
//
// Single-variable probe vs round 7: IDENTICAL one-shot structure (4096
// blocks x 4 waves, 16 words/wave as 4 quads, prologue char loads, four
// back-to-back DS chains on the in-order DS pipe), but ALL 16 nontemporal
// stores are batched into one uninterrupted 16 KiB burst at the end
// (payload held in 64 VGPRs). Mechanism under test: per-wave store-queue
// depth / long contiguous write bursts for the HBM scheduler, the one
// profile property of the 6.8 TB/s fill reference not yet imitated.
// LDS safety: quad i's ds_reads are issued before quad i+1's ds_writes;
// the DS pipe is in-order per wave and tiles are wave-private.

constexpr int WORD_LEN = 32;
constexpr int VOCAB    = 256;
constexpr int WAVES_PER_BLOCK = 4;    // 256 threads
constexpr int WORDS_PER_WAVE  = 16;   // 4 quads

typedef float f32x4 __attribute__((ext_vector_type(4)));
typedef int   i32x2 __attribute__((ext_vector_type(2)));

__global__ __launch_bounds__(256) void fofe_kernel(
    const int* __restrict__ x,
    const float* __restrict__ fptr,
    float* __restrict__ out,
    int num_words)
{
    // [wave][word-in-quad][vocab] : 16 KiB per block; all 4 stages reuse
    // the same 4 tiles sequentially (DS program order keeps it safe)
    __shared__ float tiles[WAVES_PER_BLOCK][4][VOCAB];

    const int lane = threadIdx.x & 63;
    const int wv   = threadIdx.x >> 6;
    const int grp  = lane >> 4;          // which word of the quad (0..3)
    const int j    = lane & 15;          // char-pair index: positions 2j, 2j+1

    const int gw = blockIdx.x * WAVES_PER_BLOCK + wv;      // global wave id
    const int w0 = gw * WORDS_PER_WAVE;                    // first word

    const i32x2* x2 = reinterpret_cast<const i32x2*>(x);   // 16 i32x2 per word

    // ---- prologue: issue all 4 quads' char loads ----
    i32x2 c[4];
#pragma unroll
    for (int q = 0; q < 4; ++q) {
        c[q] = (i32x2)(0);
        if (w0 + 4 * q + grp < num_words)
            c[q] = x2[(size_t)(w0 + 4 * q) * 16 + lane];
    }

    const float f  = *fptr;
    const float lf = __log2f(f);

    float (*mytiles)[VOCAB] = tiles[wv];
    float*  tile = mytiles[grp];                            // this lane's word tile
    f32x4*  t4   = reinterpret_cast<f32x4*>(mytiles);       // 256 f32x4 (all 4 tiles)

    f32x4 v[16];   // 4 quads x 4 readback vectors = 64 VGPRs of store payload

    // ---- four DS chains queued back-to-back; NO stores yet ----
#pragma unroll
    for (int q = 0; q < 4; ++q) {
        const i32x2 cc = c[q];

        const bool nzE = (cc.x != 0);
        const bool nzO = (cc.y != 0);
        const unsigned long long mE = __ballot(nzE);
        const unsigned long long mO = __ballot(nzO);
        const unsigned int mEg = (unsigned int)(mE >> (grp * 16)) & 0xFFFFu;
        const unsigned int mOg = (unsigned int)(mO >> (grp * 16)) & 0xFFFFu;
        // nonzeros strictly after position 2j / 2j+1 within this word:
        const int sE = __popc(mEg >> (j + 1)) + __popc(mOg >> j);
        const int sO = __popc(mEg >> (j + 1)) + __popc(mOg >> (j + 1));

        float wE = 0.0f, wO = 0.0f;
        if (nzE) wE = (sE == 0) ? 1.0f : exp2f((float)sE * lf);
        if (nzO) wO = (sO == 0) ? 1.0f : exp2f((float)sO * lf);

        // zero all 4 tiles: 4 KiB = 4 x ds_write_b128 per lane
        const f32x4 z = (f32x4)(0.0f);
        t4[lane]       = z;
        t4[lane + 64]  = z;
        t4[lane + 128] = z;
        t4[lane + 192] = z;

        // scatter (wave-private tiles; DS pipe in-order => no barrier)
        if (nzE) atomicAdd(&tile[cc.x], wE);
        if (nzO) atomicAdd(&tile[cc.y], wO);

        // queue readback into this quad's payload registers
        v[4 * q + 0] = t4[lane];
        v[4 * q + 1] = t4[lane + 64];
        v[4 * q + 2] = t4[lane + 128];
        v[4 * q + 3] = t4[lane + 192];
    }

    // ---- one uninterrupted 16 KiB nt store burst ----
    f32x4* o4 = reinterpret_cast<f32x4*>(out + (size_t)w0 * VOCAB);
#pragma unroll
    for (int i = 0; i < 16; ++i) {
        if (w0 + i < num_words)   // i indexes words here: v[i] is word w0+i's slice
            __builtin_nontemporal_store(v[i], &o4[lane + 64 * i]);
    }
}

extern "C" void kernel_launch(void* const* d_in, const int* in_sizes, int n_in,
                              void* d_out, int out_size, void* d_ws, size_t ws_size,
                              hipStream_t stream)
{
    const int*   x    = (const int*)d_in[0];
    const float* fptr = (const float*)d_in[1];
    float*       out  = (float*)d_out;

    const int num_words = in_sizes[0] / WORD_LEN;
    const int waves  = (num_words + WORDS_PER_WAVE - 1) / WORDS_PER_WAVE;
    const int blocks = (waves + WAVES_PER_BLOCK - 1) / WAVES_PER_BLOCK;

    fofe_kernel<<<blocks, 256, 0, stream>>>(x, fptr, out, num_words);
}